// Round 7
// baseline (1261.637 us; speedup 1.0000x reference)
//
#include <hip/hip_runtime.h>

// GRU, T=4096, B=256, I=2, H=32, O=1. Only batch row 255 reaches the output.
// Single-wave sequential recurrence; latency-bound on the h->h dependency cycle.
//
// R10: empirical ledger: R3 (2 dots + shfl_xor) 417 cy/step beats R9 (3 dots,
// no shfl) 471 and R5 (DPP trees) 533. The irreducible cross-32 transfer of r
// is moved OFF the serial chain by publishing h's INGREDIENTS instead of h:
//   hi lanes publish zz = sigmoid(z-row)   (native, no exchange)
//   lo lanes publish nv = tanh(xn + rr*hn) (rr native to lo, no exchange)
// Readers keep h in registers and reconstruct h'_k = fma(zz_k, h_k-nv_k, nv_k)
// (bitwise-identical to R3's update -> absmax 0). The exchange thus rides the
// LDS round-trip we already pay; the shfl (~110 cy serial) is deleted for
// +8 ds_read_b128 and 32 pk-ops of recon that hide in the read window.
// Since every lane holds all of h, the FC projection folds into the loop
// (16 pk_fma off-chain, uniform result, lane-0 store): fc_out kernel, hbuf,
// and 512 KB of stores are gone.

#define TT 4096

typedef float v2f __attribute__((ext_vector_type(2)));

__device__ __forceinline__ v2f fma2(v2f a, v2f b, v2f c) {
    return __builtin_elementwise_fma(a, b, c);
}
__device__ __forceinline__ float rl(float v, int l) {
    return __int_as_float(__builtin_amdgcn_readlane(__float_as_int(v), l));
}
__device__ __forceinline__ float fexp2(float x) { return __builtin_amdgcn_exp2f(x); }
__device__ __forceinline__ float frcp(float x)  { return __builtin_amdgcn_rcpf(x); }
__device__ __forceinline__ float pin(float x)   { asm volatile("" : "+v"(x)); return x; }

#define NLOG2E  (-1.44269504088896340736f)   // r/z dots pre-scaled by this
#define TLOG2E  ( 2.88539008177792681472f)   // n dot pre-scaled by this

__global__
__attribute__((amdgpu_flat_work_group_size(64, 64), amdgpu_waves_per_eu(1, 1)))
void gru_fused(
    const float* __restrict__ x,
    const float* __restrict__ w_ih,
    const float* __restrict__ w_hh,
    const float* __restrict__ b_ih,
    const float* __restrict__ b_hh,
    const float* __restrict__ w_fc,
    const float* __restrict__ b_fc,
    float* __restrict__ out)
{
    // hsm[0..31] = zz (written by hi lanes), hsm[32..63] = nv (by lo lanes)
    __shared__ float hsm[64];

    const int lane = threadIdx.x;
    const int low  = lane & 31;
    const bool lo_half = lane < 32;
    const int row0 = lane;        // rz row: r on lanes 0..31, z on 32..63
    const int row1 = 64 + low;    // n row (duplicated across halves)

    // --- weights (R3 layout): rz row + n row per lane, pre-scaled, pinned ---
    const v2f* w_hh2 = (const v2f*)w_hh;
    v2f wrz[16], wn[16];
#pragma unroll
    for (int k = 0; k < 16; ++k) {
        v2f a = w_hh2[row0 * 16 + k] * NLOG2E;
        v2f b = w_hh2[row1 * 16 + k] * TLOG2E;
        wrz[k].x = pin(a.x); wrz[k].y = pin(a.y);
        wn[k].x  = pin(b.x); wn[k].y  = pin(b.y);
    }
    const float wi00  = pin(w_ih[row0 * 2 + 0] * NLOG2E);
    const float wi01  = pin(w_ih[row0 * 2 + 1] * NLOG2E);
    const float wi10  = pin(w_ih[row1 * 2 + 0] * TLOG2E);
    const float wi11  = pin(w_ih[row1 * 2 + 1] * TLOG2E);
    const float bias0 = pin((b_ih[row0] + b_hh[row0]) * NLOG2E); // rz biases
    const float bi1   = pin(b_ih[row1] * TLOG2E);                // n: outside r*()
    const float bh1   = pin(b_hh[row1] * TLOG2E);                // n: inside r*()

    // FC weights as pairs + bias
    const v2f* wfc2 = (const v2f*)w_fc;
    v2f wfc[16];
#pragma unroll
    for (int k = 0; k < 16; ++k) {
        v2f c = wfc2[k];
        wfc[k].x = pin(c.x); wfc[k].y = pin(c.y);
    }
    const float bfc = pin(b_fc[0]);

    // h kept in registers as pairs on EVERY lane; h_0 = 0.
    v2f hp[16];
#pragma unroll
    for (int k = 0; k < 16; ++k) hp[k] = (v2f){0.0f, 0.0f};

    hsm[lane] = 0.0f;   // zz = 0, nv = 0 -> recon at t=0 keeps h = 0

    // publish address: hi lane 32+j -> hsm[j] (zz), lo lane j -> hsm[32+j] (nv)
    const int paddr = lane ^ 32;

    // x[t, 255, 0:2] as float2 at index t*256+255; 64 steps per lane-load,
    // prefetched one block ahead.
    const float2* xp = (const float2*)x;
    float2 xv = xp[(size_t)lane * 256 + 255];

    const float4* h4 = (const float4*)hsm;

    for (int tb = 0; tb < 64; ++tb) {
        float2 xv_next = xv;
        if (tb < 63) xv_next = xp[((size_t)(tb + 1) * 64 + lane) * 256 + 255];

#pragma unroll 2
        for (int i = 0; i < 64; ++i) {
            const int t = tb * 64 + i;

            // ---- read zz[0..31] and nv[0..31]: 16 x ds_read_b128 ----
            float4 zq[8], nq[8];
#pragma unroll
            for (int k = 0; k < 8; ++k) zq[k] = h4[k];
#pragma unroll
            for (int k = 0; k < 8; ++k) nq[k] = h4[8 + k];

            // ---- recon h' = nv + zz*(h - nv), packed (bitwise == R3) ----
#pragma unroll
            for (int k = 0; k < 8; ++k) {
                v2f zl = {zq[k].x, zq[k].y}, zh = {zq[k].z, zq[k].w};
                v2f nl = {nq[k].x, nq[k].y}, nh = {nq[k].z, nq[k].w};
                hp[2 * k]     = fma2(zl, hp[2 * k]     - nl, nl);
                hp[2 * k + 1] = fma2(zh, hp[2 * k + 1] - nh, nh);
            }

            // ---- FC fold: out[t-1] = dot(h_t, w_fc) + b_fc (off-chain) ----
            v2f f0 = {0.f, 0.f}, f1 = {0.f, 0.f};
#pragma unroll
            for (int k = 0; k < 8; ++k) {
                f0 = fma2(hp[2 * k],     wfc[2 * k],     f0);
                f1 = fma2(hp[2 * k + 1], wfc[2 * k + 1], f1);
            }
            v2f fs = f0 + f1;
            const float ov = fs.x + fs.y + bfc;
            if (lane == 0) out[(t + TT - 1) & (TT - 1)] = ov;  // t=0 slot fixed by peel

            // ---- x gates (off-chain) ----
            const float x0 = rl(xv.x, i);
            const float x1 = rl(xv.y, i);
            const float base0 = fmaf(x1, wi01, fmaf(x0, wi00, bias0)); // scaled
            const float xn    = fmaf(x1, wi11, fmaf(x0, wi10, bi1));   // scaled

            // ---- dots: rz row + n row over h' ----
            v2f arz0 = {base0, 0.0f}, arz1 = {0.0f, 0.0f};
            v2f an0  = {bh1,   0.0f}, an1  = {0.0f, 0.0f};
#pragma unroll
            for (int k = 0; k < 8; ++k) {
                arz0 = fma2(hp[2 * k],     wrz[2 * k],     arz0);
                arz1 = fma2(hp[2 * k + 1], wrz[2 * k + 1], arz1);
                an0  = fma2(hp[2 * k],     wn[2 * k],      an0);
                an1  = fma2(hp[2 * k + 1], wn[2 * k + 1],  an1);
            }
            v2f srz = arz0 + arz1;
            v2f sn  = an0 + an1;
            const float pre_s = srz.x + srz.y;  // -log2e * (rz pre-act)
            const float hn_s  = sn.x + sn.y;    // 2log2e * (n hidden dot + b_hh)

            // ---- activations: sg = sigma(own rz row) ----
            const float sg = frcp(1.0f + fexp2(pre_s));
            // lo lanes: rr = sg (native) -> nv; hi lanes: nv is garbage (unused)
            const float nv = fmaf(-2.0f, frcp(1.0f + fexp2(fmaf(sg, hn_s, xn))), 1.0f);

            // ---- publish: hi writes zz=sg to hsm[low], lo writes nv to hsm[32+low]
            hsm[paddr] = lo_half ? nv : sg;
        }
        xv = xv_next;
    }

    // ---- final peel: recon h_4096 from the t=4095 publish; out[4095] ----
    {
        float4 zq[8], nq[8];
#pragma unroll
        for (int k = 0; k < 8; ++k) zq[k] = h4[k];
#pragma unroll
        for (int k = 0; k < 8; ++k) nq[k] = h4[8 + k];
#pragma unroll
        for (int k = 0; k < 8; ++k) {
            v2f zl = {zq[k].x, zq[k].y}, zh = {zq[k].z, zq[k].w};
            v2f nl = {nq[k].x, nq[k].y}, nh = {nq[k].z, nq[k].w};
            hp[2 * k]     = fma2(zl, hp[2 * k]     - nl, nl);
            hp[2 * k + 1] = fma2(zh, hp[2 * k + 1] - nh, nh);
        }
        v2f f0 = {0.f, 0.f}, f1 = {0.f, 0.f};
#pragma unroll
        for (int k = 0; k < 8; ++k) {
            f0 = fma2(hp[2 * k],     wfc[2 * k],     f0);
            f1 = fma2(hp[2 * k + 1], wfc[2 * k + 1], f1);
        }
        v2f fs = f0 + f1;
        const float ov = fs.x + fs.y + bfc;
        if (lane == 0) out[TT - 1] = ov;
    }
}

extern "C" void kernel_launch(void* const* d_in, const int* in_sizes, int n_in,
                              void* d_out, int out_size, void* d_ws, size_t ws_size,
                              hipStream_t stream) {
    const float* x    = (const float*)d_in[0];
    const float* w_ih = (const float*)d_in[1];
    const float* w_hh = (const float*)d_in[2];
    const float* b_ih = (const float*)d_in[3];
    const float* b_hh = (const float*)d_in[4];
    const float* w_fc = (const float*)d_in[5];
    const float* b_fc = (const float*)d_in[6];
    float* out = (float*)d_out;

    gru_fused<<<1, 64, 0, stream>>>(x, w_ih, w_hh, b_ih, b_hh, w_fc, b_fc, out);
}

// Round 8
// 847.856 us; speedup vs baseline: 1.4880x; 1.4880x over previous
//
#include <hip/hip_runtime.h>

// GRU, T=4096, B=256, I=2, H=32, O=1. Only batch row 255 reaches the output.
// Single-wave sequential recurrence; latency-bound on the h->h dependency cycle.
//
// R11: ladder: R3 (2 dots+shfl) 417 cy/step, R9 (3 dots) 471, R5 (DPP) 533,
// R10 (2x reads + recon-on-chain) 705. R9-R3 = +54 proves the shfl costs only
// ~30-40 cy, NOT ~110; reads + dot depth + activations dominate. This round
// shortens every chain term vs R3 via COLUMN-SPLIT:
//   lane (low, hi) computes all 3 gate rows (low, 32+low, 64+low) over its
//   16-column half [16*hi, 16*hi+16):
//   - 4x ds_read_b128 instead of 8 (16 h values)
//   - dot depth 4 instead of 8 (24 fma2 issue vs 32)
//   - 3 independent __shfl_xor(,32) partial combines (verified R3 primitive;
//     permlane stays banned); only the r-combine is on the serial chain
//   - commutative own+shfl sum -> halves bitwise identical; sigma/tanh/h'
//     lane-local (R9-verified). Biases added AFTER combine (else doubled).
// Chain: read(~130) + rdot(16) + shfl(~40) + add + sigma(28) + tanh(~45) + h'
// ~= 270 raw, ~340-390 measured-model. hbuf + fc_out kept (R10: FC-fold not
// the issue).

#define TT 4096

typedef float v2f __attribute__((ext_vector_type(2)));

__device__ __forceinline__ v2f fma2(v2f a, v2f b, v2f c) {
    return __builtin_elementwise_fma(a, b, c);
}
__device__ __forceinline__ float rl(float v, int l) {
    return __int_as_float(__builtin_amdgcn_readlane(__float_as_int(v), l));
}
__device__ __forceinline__ float fexp2(float x) { return __builtin_amdgcn_exp2f(x); }
__device__ __forceinline__ float frcp(float x)  { return __builtin_amdgcn_rcpf(x); }
__device__ __forceinline__ float pin(float x)   { asm volatile("" : "+v"(x)); return x; }

#define NLOG2E  (-1.44269504088896340736f)   // r/z dots pre-scaled by this
#define TLOG2E  ( 2.88539008177792681472f)   // n dot pre-scaled by this

__global__
__attribute__((amdgpu_flat_work_group_size(64, 64), amdgpu_waves_per_eu(1, 1)))
void gru_seq(
    const float* __restrict__ x,
    const float* __restrict__ w_ih,
    const float* __restrict__ w_hh,
    const float* __restrict__ b_ih,
    const float* __restrict__ b_hh,
    float* __restrict__ hbuf)
{
    __shared__ float hsm[64];

    const int lane = threadIdx.x;
    const int low  = lane & 31;
    const int hi   = lane >> 5;      // column half: cols [16*hi, 16*hi+16)
    const int cb   = hi << 4;        // 0 or 16
    const int rrow = low;            // r gate row
    const int zrow = 32 + low;       // z gate row
    const int nrow = 64 + low;       // n gate row

    // --- weights: 3 rows x 16 cols per lane, pre-scaled, pinned ---
    const v2f* w_hh2 = (const v2f*)w_hh;   // rows of 16 v2f
    const int co = (cb >> 1);              // v2f offset within row: 0 or 8
    v2f wr[8], wz[8], wn[8];
#pragma unroll
    for (int k = 0; k < 8; ++k) {
        v2f a = w_hh2[rrow * 16 + co + k] * NLOG2E;
        v2f b = w_hh2[zrow * 16 + co + k] * NLOG2E;
        v2f c = w_hh2[nrow * 16 + co + k] * TLOG2E;
        wr[k].x = pin(a.x); wr[k].y = pin(a.y);
        wz[k].x = pin(b.x); wz[k].y = pin(b.y);
        wn[k].x = pin(c.x); wn[k].y = pin(c.y);
    }
    const float wir0 = pin(w_ih[rrow * 2 + 0] * NLOG2E);
    const float wir1 = pin(w_ih[rrow * 2 + 1] * NLOG2E);
    const float wiz0 = pin(w_ih[zrow * 2 + 0] * NLOG2E);
    const float wiz1 = pin(w_ih[zrow * 2 + 1] * NLOG2E);
    const float win0 = pin(w_ih[nrow * 2 + 0] * TLOG2E);
    const float win1 = pin(w_ih[nrow * 2 + 1] * TLOG2E);
    const float bsr  = pin((b_ih[rrow] + b_hh[rrow]) * NLOG2E);
    const float bsz  = pin((b_ih[zrow] + b_hh[zrow]) * NLOG2E);
    const float bin_ = pin(b_ih[nrow] * TLOG2E);   // outside r*(...)
    const float bhn  = pin(b_hh[nrow] * TLOG2E);   // inside  r*(...)

    hsm[lane] = 0.0f;          // single wave: DS pipe in-order, no barrier
    float h_el = 0.0f;         // this lane's h[low] (both halves identical)
    float hacc[4];             // 4-step store batch (float4)

    // x[t, 255, 0:2] as float2 at index t*256+255; 64 steps per lane-load,
    // prefetched one block ahead.
    const float2* xp = (const float2*)x;
    float2 xv = xp[(size_t)lane * 256 + 255];

    const float4* h4 = (const float4*)hsm;
    const int rb = cb >> 2;    // float4 read base: 0 or 4

    for (int tb = 0; tb < 64; ++tb) {
        float2 xv_next = xv;
        if (tb < 63) xv_next = xp[((size_t)(tb + 1) * 64 + lane) * 256 + 255];
        // transposed layout: hbuf[j*TT + t], t = tb*64 + i
        float4* hout = (float4*)(hbuf + (size_t)low * TT + tb * 64);

#pragma unroll 4
        for (int i = 0; i < 64; ++i) {
            // read this lane's 16 h values: 4 x ds_read_b128
            // (2 distinct addrs per instr across halves -> different banks,
            //  broadcast within each half)
            float4 hq[4];
#pragma unroll
            for (int k = 0; k < 4; ++k) hq[k] = h4[rb + k];

            const float x0 = rl(xv.x, i);
            const float x1 = rl(xv.y, i);
            const float br = fmaf(x1, wir1, fmaf(x0, wir0, bsr));   // scaled
            const float bz = fmaf(x1, wiz1, fmaf(x0, wiz0, bsz));   // scaled
            const float xn = fmaf(x1, win1, fmaf(x0, win0, bin_));  // scaled

            // ---- r partial first (gates the serial chain), shfl early ----
            v2f ar0 = {0.f, 0.f}, ar1 = {0.f, 0.f};
#pragma unroll
            for (int k = 0; k < 4; ++k) {
                v2f hl = {hq[k].x, hq[k].y};
                v2f hh = {hq[k].z, hq[k].w};
                ar0 = fma2(hl, wr[2 * k],     ar0);
                ar1 = fma2(hh, wr[2 * k + 1], ar1);
            }
            v2f sr = ar0 + ar1;
            const float prp = sr.x + sr.y;
            const float prx = __shfl_xor(prp, 32);

            v2f az0 = {0.f, 0.f}, az1 = {0.f, 0.f};
#pragma unroll
            for (int k = 0; k < 4; ++k) {
                v2f hl = {hq[k].x, hq[k].y};
                v2f hh = {hq[k].z, hq[k].w};
                az0 = fma2(hl, wz[2 * k],     az0);
                az1 = fma2(hh, wz[2 * k + 1], az1);
            }
            v2f szv = az0 + az1;
            const float pzp = szv.x + szv.y;
            const float pzx = __shfl_xor(pzp, 32);

            v2f an0 = {0.f, 0.f}, an1 = {0.f, 0.f};
#pragma unroll
            for (int k = 0; k < 4; ++k) {
                v2f hl = {hq[k].x, hq[k].y};
                v2f hh = {hq[k].z, hq[k].w};
                an0 = fma2(hl, wn[2 * k],     an0);
                an1 = fma2(hh, wn[2 * k + 1], an1);
            }
            v2f snv = an0 + an1;
            const float pnp = snv.x + snv.y;
            const float pnx = __shfl_xor(pnp, 32);

            // combines: commutative own+other -> bitwise identical halves;
            // biases AFTER the combine
            const float pre_r = (prp + prx) + br;
            const float rr    = frcp(1.0f + fexp2(pre_r));   // sigmoid(r)
            const float pre_z = (pzp + pzx) + bz;
            const float zz    = frcp(1.0f + fexp2(pre_z));   // sigmoid(z)
            const float hn_s  = (pnp + pnx) + bhn;

            // n = tanh(xn + r*hn); arg pre-scaled by 2log2e
            const float nv = fmaf(-2.0f, frcp(1.0f + fexp2(fmaf(rr, hn_s, xn))), 1.0f);
            h_el = fmaf(zz, h_el - nv, nv);     // h = n + z*(h-n)

            hsm[lane] = h_el;                   // publish for next step
            hacc[i & 3] = h_el;
            if ((i & 3) == 3) hout[i >> 2] = *(const float4*)hacc;
        }
        xv = xv_next;
    }
}

// out[t] = sum_j hbuf[j*TT + t] * w_fc[j] + b_fc   (transposed hbuf)
__global__ void fc_out(const float* __restrict__ hbuf,
                       const float* __restrict__ w_fc,
                       const float* __restrict__ b_fc,
                       float* __restrict__ out)
{
    const int t = blockIdx.x * blockDim.x + threadIdx.x;
    if (t >= TT) return;
    float acc = 0.f;
#pragma unroll
    for (int j = 0; j < 32; ++j) acc = fmaf(hbuf[j * TT + t], w_fc[j], acc);
    out[t] = acc + b_fc[0];
}

extern "C" void kernel_launch(void* const* d_in, const int* in_sizes, int n_in,
                              void* d_out, int out_size, void* d_ws, size_t ws_size,
                              hipStream_t stream) {
    const float* x    = (const float*)d_in[0];
    const float* w_ih = (const float*)d_in[1];
    const float* w_hh = (const float*)d_in[2];
    const float* b_ih = (const float*)d_in[3];
    const float* b_hh = (const float*)d_in[4];
    const float* w_fc = (const float*)d_in[5];
    const float* b_fc = (const float*)d_in[6];
    float* out  = (float*)d_out;
    float* hbuf = (float*)d_ws;   // 32*TT*4 = 512 KB

    gru_seq<<<1, 64, 0, stream>>>(x, w_ih, w_hh, b_ih, b_hh, hbuf);
    fc_out<<<TT / 256, 256, 0, stream>>>(hbuf, w_fc, b_fc, out);
}